// Round 1
// baseline (186.352 us; speedup 1.0000x reference)
//
#include <hip/hip_runtime.h>

#define NN 50000
#define NE 800000
#define DD 128
#define DOUTC 128
#define SLOT_CAP 64

// ws layout (bytes):
//   [0,        200000)   cnt   : int[NN]
//   [262144, 13062144)   slots : int[NN*SLOT_CAP]
//   [13062144,38662144)  Xnbr  : float[NN*DD]

__global__ __launch_bounds__(256) void k_zero(int* __restrict__ cnt) {
  int i = blockIdx.x * 256 + threadIdx.x;
  if (i < NN) cnt[i] = 0;
}

__global__ __launch_bounds__(256) void k_scatter(const int* __restrict__ src,
                                                 const int* __restrict__ dst,
                                                 int* __restrict__ cnt,
                                                 int* __restrict__ slots) {
  int e = blockIdx.x * 256 + threadIdx.x;
  if (e >= NE) return;
  int d = dst[e];
  int pos = atomicAdd(&cnt[d], 1);
  if (pos < SLOT_CAP) slots[d * SLOT_CAP + pos] = src[e];
}

// one wave per node: lane l owns dims [2l, 2l+1]
__global__ __launch_bounds__(256) void k_aggregate(const float* __restrict__ X,
                                                   const int* __restrict__ cnt,
                                                   const int* __restrict__ slots,
                                                   float* __restrict__ Xnbr) {
  int lane = threadIdx.x & 63;
  int node = blockIdx.x * 4 + (threadIdx.x >> 6);
  if (node >= NN) return;
  int deg = cnt[node];
  int m = min(deg, SLOT_CAP);
  int sid = 0;
  if (lane < m) sid = slots[node * SLOT_CAP + lane];
  float ax = 0.f, ay = 0.f;
  for (int e = 0; e < m; ++e) {
    int s = __shfl(sid, e, 64);
    const float2 xr = *reinterpret_cast<const float2*>(X + (size_t)s * DD + lane * 2);
    ax += xr.x;
    ay += xr.y;
  }
  float inv = 1.0f / (float)max(deg, 1);
  float2 o;
  o.x = ax * inv;
  o.y = ay * inv;
  *reinterpret_cast<float2*>(Xnbr + (size_t)node * DD + lane * 2) = o;
}

// W (256x128 f32, 128KB) staged in LDS; each wave processes 8 nodes/pass.
// Node index readfirstlane'd -> h operands are wave-uniform loads (SGPR-friendly);
// lane l computes output columns {2l, 2l+1} via ds_read_b64 of W rows.
__global__ __launch_bounds__(512) void k_gemm(const float* __restrict__ X,
                                              const float* __restrict__ Xnbr,
                                              const float* __restrict__ W,
                                              const float* __restrict__ b,
                                              const int* __restrict__ mask,
                                              float* __restrict__ out) {
  __shared__ float Wlds[2 * DD * DOUTC];  // 128 KiB
  __shared__ float blds[DOUTC];
  {
    const float4* Wg = reinterpret_cast<const float4*>(W);
    float4* Wl = reinterpret_cast<float4*>(Wlds);
    for (int i = threadIdx.x; i < (2 * DD * DOUTC) / 4; i += 512) Wl[i] = Wg[i];
    if (threadIdx.x < DOUTC) blds[threadIdx.x] = b[threadIdx.x];
  }
  __syncthreads();

  int lane = threadIdx.x & 63;
  int wid = threadIdx.x >> 6;
  const float2* W2 = reinterpret_cast<const float2*>(Wlds);
  float bx = blds[2 * lane];
  float by = blds[2 * lane + 1];

  int gw = blockIdx.x * 8 + wid;
  int nwaves = gridDim.x * 8;
  for (int g0 = gw; g0 < NN / 8; g0 += nwaves) {
    int g = __builtin_amdgcn_readfirstlane(g0);
    float acc[8][2];
#pragma unroll
    for (int t = 0; t < 8; ++t) {
      acc[t][0] = 0.f;
      acc[t][1] = 0.f;
    }
    const float* hb0 = X + (size_t)g * (8 * DD);
    const float* hb1 = Xnbr + (size_t)g * (8 * DD);
    // K half 0: self features (W rows 0..127)
#pragma unroll 4
    for (int k4 = 0; k4 < DD / 4; ++k4) {
      int k = k4 * 4;
      float2 w0 = W2[(k + 0) * 64 + lane];
      float2 w1 = W2[(k + 1) * 64 + lane];
      float2 w2 = W2[(k + 2) * 64 + lane];
      float2 w3 = W2[(k + 3) * 64 + lane];
#pragma unroll
      for (int t = 0; t < 8; ++t) {
        float4 h = *reinterpret_cast<const float4*>(hb0 + t * DD + k);
        acc[t][0] = fmaf(h.x, w0.x, acc[t][0]);
        acc[t][0] = fmaf(h.y, w1.x, acc[t][0]);
        acc[t][0] = fmaf(h.z, w2.x, acc[t][0]);
        acc[t][0] = fmaf(h.w, w3.x, acc[t][0]);
        acc[t][1] = fmaf(h.x, w0.y, acc[t][1]);
        acc[t][1] = fmaf(h.y, w1.y, acc[t][1]);
        acc[t][1] = fmaf(h.z, w2.y, acc[t][1]);
        acc[t][1] = fmaf(h.w, w3.y, acc[t][1]);
      }
    }
    // K half 1: neighbor features (W rows 128..255)
#pragma unroll 4
    for (int k4 = 0; k4 < DD / 4; ++k4) {
      int k = k4 * 4;
      float2 w0 = W2[(DD + k + 0) * 64 + lane];
      float2 w1 = W2[(DD + k + 1) * 64 + lane];
      float2 w2 = W2[(DD + k + 2) * 64 + lane];
      float2 w3 = W2[(DD + k + 3) * 64 + lane];
#pragma unroll
      for (int t = 0; t < 8; ++t) {
        float4 h = *reinterpret_cast<const float4*>(hb1 + t * DD + k);
        acc[t][0] = fmaf(h.x, w0.x, acc[t][0]);
        acc[t][0] = fmaf(h.y, w1.x, acc[t][0]);
        acc[t][0] = fmaf(h.z, w2.x, acc[t][0]);
        acc[t][0] = fmaf(h.w, w3.x, acc[t][0]);
        acc[t][1] = fmaf(h.x, w0.y, acc[t][1]);
        acc[t][1] = fmaf(h.y, w1.y, acc[t][1]);
        acc[t][1] = fmaf(h.z, w2.y, acc[t][1]);
        acc[t][1] = fmaf(h.w, w3.y, acc[t][1]);
      }
    }
    // epilogue: +b, relu, dropout mask * 2
#pragma unroll
    for (int t = 0; t < 8; ++t) {
      int n = g * 8 + t;
      float rx = acc[t][0] + bx;
      float ry = acc[t][1] + by;
      int2 mk = *reinterpret_cast<const int2*>(mask + (size_t)n * DOUTC + 2 * lane);
      rx = fmaxf(rx, 0.f) * (2.0f * (float)mk.x);
      ry = fmaxf(ry, 0.f) * (2.0f * (float)mk.y);
      float2 r;
      r.x = rx;
      r.y = ry;
      *reinterpret_cast<float2*>(out + (size_t)n * DOUTC + 2 * lane) = r;
    }
  }
}

extern "C" void kernel_launch(void* const* d_in, const int* in_sizes, int n_in,
                              void* d_out, int out_size, void* d_ws, size_t ws_size,
                              hipStream_t stream) {
  (void)in_sizes; (void)n_in; (void)out_size; (void)ws_size;
  const float* X = (const float*)d_in[0];
  const float* W = (const float*)d_in[1];
  const float* b = (const float*)d_in[2];
  const int* src = (const int*)d_in[3];
  const int* dst = (const int*)d_in[4];
  const int* mask = (const int*)d_in[5];
  float* out = (float*)d_out;

  char* ws = (char*)d_ws;
  int* cnt = (int*)ws;
  int* slots = (int*)(ws + 262144);
  float* Xnbr = (float*)(ws + 13062144);

  k_zero<<<(NN + 255) / 256, 256, 0, stream>>>(cnt);
  k_scatter<<<(NE + 255) / 256, 256, 0, stream>>>(src, dst, cnt, slots);
  k_aggregate<<<(NN + 3) / 4, 256, 0, stream>>>(X, cnt, slots, Xnbr);
  k_gemm<<<256, 512, 0, stream>>>(X, Xnbr, W, b, mask, out);
}

// Round 2
// 138.995 us; speedup vs baseline: 1.3407x; 1.3407x over previous
//
#include <hip/hip_runtime.h>

#define NN 50000
#define NE 800000
#define SLOT_CAP 56
#define NTILE 3125  // NN / 16

typedef __attribute__((ext_vector_type(8))) short short8;
typedef __attribute__((ext_vector_type(4))) float f32x4;
typedef __attribute__((ext_vector_type(4))) unsigned int u32x4;
typedef __attribute__((ext_vector_type(2))) unsigned int u32x2;

// ws layout (bytes):
//   [0,          200000)   cnt   : int[NN]
//   [200704,     266240)   Wfrag : u32x4[4096]   (64 KiB, MFMA B-fragment order)
//   [266240,   11466240)   slots : int[NN*SLOT_CAP]
//   [11466240, 24266240)   Xbf   : bf16[NN*128]
//   [24266240, 37066240)   Xnbr  : bf16[NN*128]

__device__ __forceinline__ unsigned short f2bf(float f) {  // RNE f32->bf16
  unsigned int u = __builtin_bit_cast(unsigned int, f);
  return (unsigned short)((u + 0x7fffu + ((u >> 16) & 1u)) >> 16);
}
__device__ __forceinline__ float bflo(unsigned int u) {
  return __builtin_bit_cast(float, u << 16);
}
__device__ __forceinline__ float bfhi(unsigned int u) {
  return __builtin_bit_cast(float, u & 0xffff0000u);
}

__global__ __launch_bounds__(256) void k_convert(const float* __restrict__ X,
                                                 unsigned short* __restrict__ Xbf) {
  int i = blockIdx.x * 256 + threadIdx.x;  // one float4 per thread
  if (i >= (NN * 128) / 4) return;
  f32x4 v = *((const f32x4*)X + i);
  u32x2 o;
  o[0] = (unsigned)f2bf(v[0]) | ((unsigned)f2bf(v[1]) << 16);
  o[1] = (unsigned)f2bf(v[2]) | ((unsigned)f2bf(v[3]) << 16);
  *((u32x2*)Xbf + i) = o;
}

// Pack W (256x128 f32, row-major) into MFMA B-fragment order:
// slot s = (kb*8 + t)*64 + lane; element i of lane = W[kb*32+(lane>>4)*8+i][t*16+(lane&15)]
__global__ __launch_bounds__(512) void k_convert_w(const float* __restrict__ W,
                                                   u32x4* __restrict__ Wfrag) {
  int s = blockIdx.x * 512 + threadIdx.x;
  if (s >= 4096) return;
  int lane = s & 63;
  int t = (s >> 6) & 7;
  int kb = s >> 9;
  int col = t * 16 + (lane & 15);
  int k0 = kb * 32 + (lane >> 4) * 8;
  u32x4 o;
#pragma unroll
  for (int p = 0; p < 4; ++p) {
    float lo = W[(k0 + 2 * p) * 128 + col];
    float hi = W[(k0 + 2 * p + 1) * 128 + col];
    o[p] = (unsigned)f2bf(lo) | ((unsigned)f2bf(hi) << 16);
  }
  Wfrag[s] = o;
}

__global__ __launch_bounds__(256) void k_scatter(const int* __restrict__ src,
                                                 const int* __restrict__ dst,
                                                 int* __restrict__ cnt,
                                                 int* __restrict__ slots) {
  int e = blockIdx.x * 256 + threadIdx.x;
  if (e >= NE) return;
  int d = dst[e];
  int pos = atomicAdd(&cnt[d], 1);
  if (pos < SLOT_CAP) slots[d * SLOT_CAP + pos] = src[e];
}

// one wave per node: lane l owns bf16 dims [2l, 2l+1] (4B per lane, 256B per row)
__global__ __launch_bounds__(256) void k_aggregate(const unsigned short* __restrict__ Xbf,
                                                   const int* __restrict__ cnt,
                                                   const int* __restrict__ slots,
                                                   unsigned short* __restrict__ Xnbr) {
  int lane = threadIdx.x & 63;
  int node = blockIdx.x * 4 + (threadIdx.x >> 6);
  if (node >= NN) return;
  int deg = cnt[node];
  int m = min(deg, SLOT_CAP);
  int sid = 0;
  if (lane < m) sid = slots[node * SLOT_CAP + lane];
  float ax = 0.f, ay = 0.f;
  for (int e = 0; e < m; ++e) {
    int s = __shfl(sid, e, 64);
    unsigned int xr = *(const unsigned int*)(Xbf + (size_t)s * 128 + lane * 2);
    ax += bflo(xr);
    ay += bfhi(xr);
  }
  float inv = 1.0f / (float)max(deg, 1);
  unsigned int o = (unsigned)f2bf(ax * inv) | ((unsigned)f2bf(ay * inv) << 16);
  *(unsigned int*)(Xnbr + (size_t)node * 128 + lane * 2) = o;
}

// MFMA GEMM: out[50000x128] = relu(concat(X,Xnbr) @ W + b) * mask*2
// one wave per 16-row tile; B-frags straight from L2 (Wfrag, 64KB); no LDS.
__global__ __launch_bounds__(512) void k_gemm(const unsigned short* __restrict__ Xbf,
                                              const unsigned short* __restrict__ Xnbr,
                                              const u32x4* __restrict__ Wfrag,
                                              const float* __restrict__ b,
                                              const int* __restrict__ mask,
                                              float* __restrict__ out) {
  int lane = threadIdx.x & 63;
  int wid = threadIdx.x >> 6;
  int tile = blockIdx.x * 8 + wid;
  if (tile >= NTILE) return;

  int row = tile * 16 + (lane & 15);
  const u32x4* a0 = (const u32x4*)(Xbf + (size_t)row * 128) + (lane >> 4);
  const u32x4* a1 = (const u32x4*)(Xnbr + (size_t)row * 128) + (lane >> 4);

  float bias[8];
#pragma unroll
  for (int t = 0; t < 8; ++t) bias[t] = b[t * 16 + (lane & 15)];

  f32x4 acc[8];
#pragma unroll
  for (int t = 0; t < 8; ++t) acc[t] = (f32x4){0.f, 0.f, 0.f, 0.f};

#pragma unroll
  for (int kb = 0; kb < 4; ++kb) {
    short8 a = __builtin_bit_cast(short8, a0[kb * 4]);
#pragma unroll
    for (int t = 0; t < 8; ++t) {
      short8 w = __builtin_bit_cast(short8, Wfrag[(kb * 8 + t) * 64 + lane]);
      acc[t] = __builtin_amdgcn_mfma_f32_16x16x32_bf16(a, w, acc[t], 0, 0, 0);
    }
  }
#pragma unroll
  for (int kb = 0; kb < 4; ++kb) {
    short8 a = __builtin_bit_cast(short8, a1[kb * 4]);
#pragma unroll
    for (int t = 0; t < 8; ++t) {
      short8 w = __builtin_bit_cast(short8, Wfrag[((kb + 4) * 8 + t) * 64 + lane]);
      acc[t] = __builtin_amdgcn_mfma_f32_16x16x32_bf16(a, w, acc[t], 0, 0, 0);
    }
  }

  // epilogue: C/D frag: col = lane&15 (+16t), row = (lane>>4)*4 + reg
  int orow = tile * 16 + (lane >> 4) * 4;
  int ocol = lane & 15;
#pragma unroll
  for (int t = 0; t < 8; ++t) {
#pragma unroll
    for (int rg = 0; rg < 4; ++rg) {
      size_t idx = (size_t)(orow + rg) * 128 + t * 16 + ocol;
      float v = fmaxf(acc[t][rg] + bias[t], 0.f);
      int mk = mask[idx];
      out[idx] = v * (2.0f * (float)mk);
    }
  }
}

extern "C" void kernel_launch(void* const* d_in, const int* in_sizes, int n_in,
                              void* d_out, int out_size, void* d_ws, size_t ws_size,
                              hipStream_t stream) {
  (void)in_sizes; (void)n_in; (void)out_size; (void)ws_size;
  const float* X = (const float*)d_in[0];
  const float* W = (const float*)d_in[1];
  const float* b = (const float*)d_in[2];
  const int* src = (const int*)d_in[3];
  const int* dst = (const int*)d_in[4];
  const int* mask = (const int*)d_in[5];
  float* out = (float*)d_out;

  char* ws = (char*)d_ws;
  int* cnt = (int*)ws;
  u32x4* Wfrag = (u32x4*)(ws + 200704);
  int* slots = (int*)(ws + 266240);
  unsigned short* Xbf = (unsigned short*)(ws + 11466240);
  unsigned short* Xnbr = (unsigned short*)(ws + 24266240);

  hipMemsetAsync(cnt, 0, NN * sizeof(int), stream);
  k_convert<<<(NN * 128 / 4 + 255) / 256, 256, 0, stream>>>(X, Xbf);
  k_convert_w<<<8, 512, 0, stream>>>(W, Wfrag);
  k_scatter<<<(NE + 255) / 256, 256, 0, stream>>>(src, dst, cnt, slots);
  k_aggregate<<<(NN + 3) / 4, 256, 0, stream>>>(Xbf, cnt, slots, Xnbr);
  k_gemm<<<(NTILE + 7) / 8, 512, 0, stream>>>(Xbf, Xnbr, Wfrag, b, mask, out);
}

// Round 3
// 110.592 us; speedup vs baseline: 1.6850x; 1.2568x over previous
//
#include <hip/hip_runtime.h>

#define NN 50000
#define ND 50048   // padded node count (multiple of 8)
#define NW 6256    // ND/8 packed-nibble words
#define NE 800000
#define CHUNKS 128
#define EPC 6250   // NE / CHUNKS
#define CAP 64
#define NTILE 3125 // NN / 16

typedef __attribute__((ext_vector_type(8))) short short8;
typedef __attribute__((ext_vector_type(4))) float f32x4;
typedef __attribute__((ext_vector_type(4))) unsigned int u32x4;
typedef __attribute__((ext_vector_type(2))) unsigned int u32x2;

// ws layout (bytes):
//   0          Wfrag     u32x4[4096]        65,536
//   65,536     rank      u8[NE]            800,000 -> 865,536
//   865,536    deg       u32[ND]           200,192 -> 1,065,728
//   1,065,728  chunkcnt  u32[CHUNKS*NW]  3,203,072 -> 4,268,800
//   4,268,800  chunkbase u8[CHUNKS*ND]   6,406,144 -> 10,674,944
//   10,674,944 slots     int[NN*CAP]    12,800,000 -> 23,474,944
//   23,474,944 Xnbr      bf16[NN*128]   12,800,000 -> 36,274,944

__device__ __forceinline__ unsigned f2bf(float f) {  // RNE f32->bf16 (low 16 bits)
  unsigned u = __builtin_bit_cast(unsigned, f);
  return (u + 0x7fffu + ((u >> 16) & 1u)) >> 16;
}

// Per-chunk edge ranking via packed-nibble LDS histogram. Also packs W (fused).
__global__ __launch_bounds__(1024) void k_rank(const int* __restrict__ dst,
                                               const float* __restrict__ W,
                                               unsigned char* __restrict__ rank,
                                               unsigned int* __restrict__ chunkcnt,
                                               u32x4* __restrict__ Wfrag) {
  __shared__ unsigned int pack[NW];
  int tid = threadIdx.x;
  int c = blockIdx.x;
  // fused W fragment pack: slot s holds B-frag for (kb=s>>9, t=(s>>6)&7, lane=s&63)
  if (tid < 32) {
    int s = c * 32 + tid;
    int lane = s & 63;
    int t = (s >> 6) & 7;
    int kb = s >> 9;
    int col = t * 16 + (lane & 15);
    int k0 = kb * 32 + (lane >> 4) * 8;
    u32x4 o;
#pragma unroll
    for (int p = 0; p < 4; ++p) {
      unsigned lo = f2bf(W[(k0 + 2 * p) * 128 + col]);
      unsigned hi = f2bf(W[(k0 + 2 * p + 1) * 128 + col]);
      o[p] = lo | (hi << 16);
    }
    Wfrag[s] = o;
  }
  for (int w = tid; w < NW; w += 1024) pack[w] = 0;
  __syncthreads();
  int ebase = c * EPC;
  for (int i = tid; i < EPC; i += 1024) {
    int e = ebase + i;
    int d = dst[e];
    unsigned sh = (unsigned)(d & 7) * 4u;
    unsigned old = atomicAdd(&pack[d >> 3], 1u << sh);
    rank[e] = (unsigned char)((old >> sh) & 15u);
  }
  __syncthreads();
  for (int w = tid; w < NW; w += 1024) chunkcnt[(size_t)c * NW + w] = pack[w];
}

// Per-node exclusive scan over chunks -> u8 bases + total degree.
__global__ __launch_bounds__(256) void k_base(const unsigned int* __restrict__ chunkcnt,
                                              unsigned char* __restrict__ chunkbase,
                                              unsigned int* __restrict__ deg) {
  int d = blockIdx.x * 256 + threadIdx.x;
  if (d >= NN) return;
  int w = d >> 3;
  unsigned sh = (unsigned)(d & 7) * 4u;
  unsigned run = 0;
  for (int c = 0; c < CHUNKS; ++c) {
    unsigned v = (chunkcnt[(size_t)c * NW + w] >> sh) & 15u;
    chunkbase[(size_t)c * ND + d] = (unsigned char)run;
    run += v;
  }
  deg[d] = run;
}

// Fully parallel placement — no atomics.
__global__ __launch_bounds__(256) void k_place(const int* __restrict__ src,
                                               const int* __restrict__ dst,
                                               const unsigned char* __restrict__ rank,
                                               const unsigned char* __restrict__ chunkbase,
                                               int* __restrict__ slots) {
  int e = blockIdx.x * 256 + threadIdx.x;
  if (e >= NE) return;
  int c = e / EPC;
  int d = dst[e];
  int pos = (int)chunkbase[(size_t)c * ND + d] + (int)rank[e];
  if (pos < CAP) slots[d * CAP + pos] = src[e];
}

// One wave per node; edge ids via wave-uniform scalar loads; f32 gather.
__global__ __launch_bounds__(256) void k_aggregate(const float* __restrict__ X,
                                                   const unsigned int* __restrict__ deg,
                                                   const int* __restrict__ slots,
                                                   unsigned int* __restrict__ Xnbr32) {
  int lane = threadIdx.x & 63;
  int node = __builtin_amdgcn_readfirstlane(blockIdx.x * 4 + (threadIdx.x >> 6));
  if (node >= NN) return;
  int dg = (int)deg[node];
  int m = min(dg, CAP);
  const int* sl = slots + node * CAP;
  float ax0 = 0.f, ay0 = 0.f, ax1 = 0.f, ay1 = 0.f;
  int e = 0;
  for (; e + 8 <= m; e += 8) {
    int s[8];
#pragma unroll
    for (int j = 0; j < 8; ++j) s[j] = __builtin_amdgcn_readfirstlane(sl[e + j]);
    float2 v[8];
#pragma unroll
    for (int j = 0; j < 8; ++j) v[j] = *(const float2*)(X + (size_t)s[j] * 128 + lane * 2);
#pragma unroll
    for (int j = 0; j < 8; j += 2) {
      ax0 += v[j].x;
      ay0 += v[j].y;
      ax1 += v[j + 1].x;
      ay1 += v[j + 1].y;
    }
  }
  for (; e < m; ++e) {
    int s0 = __builtin_amdgcn_readfirstlane(sl[e]);
    float2 v = *(const float2*)(X + (size_t)s0 * 128 + lane * 2);
    ax0 += v.x;
    ay0 += v.y;
  }
  float inv = 1.0f / (float)max(dg, 1);
  float ax = (ax0 + ax1) * inv;
  float ay = (ay0 + ay1) * inv;
  Xnbr32[node * 64 + lane] = f2bf(ax) | (f2bf(ay) << 16);
}

// MFMA GEMM: out = relu(concat(X, Xnbr) @ W + b) * mask * 2
__global__ __launch_bounds__(512) void k_gemm(const float* __restrict__ X,
                                              const unsigned short* __restrict__ Xnbr,
                                              const u32x4* __restrict__ Wfrag,
                                              const float* __restrict__ b,
                                              const int* __restrict__ mask,
                                              float* __restrict__ out) {
  int lane = threadIdx.x & 63;
  int wid = threadIdx.x >> 6;
  int tile = blockIdx.x * 8 + wid;
  if (tile >= NTILE) return;

  int row = tile * 16 + (lane & 15);
  const float* axp = X + (size_t)row * 128 + (lane >> 4) * 8;
  const u32x4* a1 = (const u32x4*)(Xnbr + (size_t)row * 128) + (lane >> 4);

  float bias[8];
#pragma unroll
  for (int t = 0; t < 8; ++t) bias[t] = b[t * 16 + (lane & 15)];

  f32x4 acc[8];
#pragma unroll
  for (int t = 0; t < 8; ++t) acc[t] = (f32x4){0.f, 0.f, 0.f, 0.f};

#pragma unroll
  for (int kb = 0; kb < 4; ++kb) {
    f32x4 lo = *(const f32x4*)(axp + kb * 32);
    f32x4 hi = *(const f32x4*)(axp + kb * 32 + 4);
    u32x4 ap;
    ap[0] = f2bf(lo[0]) | (f2bf(lo[1]) << 16);
    ap[1] = f2bf(lo[2]) | (f2bf(lo[3]) << 16);
    ap[2] = f2bf(hi[0]) | (f2bf(hi[1]) << 16);
    ap[3] = f2bf(hi[2]) | (f2bf(hi[3]) << 16);
    short8 a = __builtin_bit_cast(short8, ap);
#pragma unroll
    for (int t = 0; t < 8; ++t) {
      short8 w = __builtin_bit_cast(short8, Wfrag[(kb * 8 + t) * 64 + lane]);
      acc[t] = __builtin_amdgcn_mfma_f32_16x16x32_bf16(a, w, acc[t], 0, 0, 0);
    }
  }
#pragma unroll
  for (int kb = 0; kb < 4; ++kb) {
    short8 a = __builtin_bit_cast(short8, a1[kb * 4]);
#pragma unroll
    for (int t = 0; t < 8; ++t) {
      short8 w = __builtin_bit_cast(short8, Wfrag[((kb + 4) * 8 + t) * 64 + lane]);
      acc[t] = __builtin_amdgcn_mfma_f32_16x16x32_bf16(a, w, acc[t], 0, 0, 0);
    }
  }

  int orow = tile * 16 + (lane >> 4) * 4;
  int ocol = lane & 15;
#pragma unroll
  for (int t = 0; t < 8; ++t) {
#pragma unroll
    for (int rg = 0; rg < 4; ++rg) {
      size_t idx = (size_t)(orow + rg) * 128 + t * 16 + ocol;
      float v = fmaxf(acc[t][rg] + bias[t], 0.f);
      int mk = mask[idx];
      out[idx] = v * (2.0f * (float)mk);
    }
  }
}

extern "C" void kernel_launch(void* const* d_in, const int* in_sizes, int n_in,
                              void* d_out, int out_size, void* d_ws, size_t ws_size,
                              hipStream_t stream) {
  (void)in_sizes; (void)n_in; (void)out_size; (void)ws_size;
  const float* X = (const float*)d_in[0];
  const float* W = (const float*)d_in[1];
  const float* b = (const float*)d_in[2];
  const int* src = (const int*)d_in[3];
  const int* dst = (const int*)d_in[4];
  const int* mask = (const int*)d_in[5];
  float* out = (float*)d_out;

  char* ws = (char*)d_ws;
  u32x4* Wfrag = (u32x4*)ws;
  unsigned char* rank = (unsigned char*)(ws + 65536);
  unsigned int* deg = (unsigned int*)(ws + 865536);
  unsigned int* chunkcnt = (unsigned int*)(ws + 1065728);
  unsigned char* chunkbase = (unsigned char*)(ws + 4268800);
  int* slots = (int*)(ws + 10674944);
  unsigned int* Xnbr32 = (unsigned int*)(ws + 23474944);
  const unsigned short* Xnbr = (const unsigned short*)Xnbr32;

  k_rank<<<CHUNKS, 1024, 0, stream>>>(dst, W, rank, chunkcnt, Wfrag);
  k_base<<<(NN + 255) / 256, 256, 0, stream>>>(chunkcnt, chunkbase, deg);
  k_place<<<(NE + 255) / 256, 256, 0, stream>>>(src, dst, rank, chunkbase, slots);
  k_aggregate<<<NN / 4, 256, 0, stream>>>(X, deg, slots, Xnbr32);
  k_gemm<<<(NTILE + 7) / 8, 512, 0, stream>>>(X, Xnbr, Wfrag, b, mask, out);
}

// Round 4
// 89.467 us; speedup vs baseline: 2.0829x; 1.2361x over previous
//
#include <hip/hip_runtime.h>

#define NN 50000
#define ND 50048   // padded node count (multiple of 8)
#define NW 6256    // ND/8 packed-nibble words
#define NE 800000
#define CHUNKS 128
#define EPC 6250   // NE / CHUNKS
#define CAP 56
#define NTILE 3125 // NN / 16
#define CVT_UNITS 1600000  // NN*128/4 (one f32x4 -> u32x2 per thread)
#define CVT_BLOCKS 1563    // ceil(CVT_UNITS/1024)

typedef __attribute__((ext_vector_type(8))) short short8;
typedef __attribute__((ext_vector_type(4))) float f32x4;
typedef __attribute__((ext_vector_type(4))) unsigned int u32x4;
typedef __attribute__((ext_vector_type(2))) unsigned int u32x2;

// ws layout (bytes):
//   0           Wfrag     u32x4[4096]         65,536
//   65,536      deg       u32[ND]            200,192 ->    265,728
//   265,728     slots     int[NN*CAP]     11,200,000 -> 11,465,728
//   11,465,728  Xbf       bf16[NN*128]    12,800,000 -> 24,265,728
//   24,265,728  Xnbr      bf16[NN*128]    12,800,000 -> 37,065,728
//     overlapped inside Xnbr region (dead before k_aggregate writes Xnbr):
//     24,265,728  rank      u8[NE]           800,000 -> 25,065,728
//     25,065,728  chunkcnt  u32[CHUNKS*NW] 3,203,072 -> 28,268,800
//     28,268,800  chunkbase u8[CHUNKS*ND]  6,406,144 -> 34,674,944

__device__ __forceinline__ unsigned f2bf(float f) {  // RNE f32->bf16 (low 16 bits)
  unsigned u = __builtin_bit_cast(unsigned, f);
  return (u + 0x7fffu + ((u >> 16) & 1u)) >> 16;
}
__device__ __forceinline__ float bflo(unsigned u) {
  return __builtin_bit_cast(float, u << 16);
}
__device__ __forceinline__ float bfhi(unsigned u) {
  return __builtin_bit_cast(float, u & 0xffff0000u);
}

// blocks < CHUNKS: per-chunk edge ranking (packed-nibble LDS histogram) + W pack.
// blocks >= CHUNKS: X f32 -> bf16 conversion.
__global__ __launch_bounds__(1024) void k_rankconv(const int* __restrict__ dst,
                                                   const float* __restrict__ W,
                                                   const float* __restrict__ X,
                                                   unsigned char* __restrict__ rank,
                                                   unsigned int* __restrict__ chunkcnt,
                                                   u32x4* __restrict__ Wfrag,
                                                   u32x2* __restrict__ Xbf2) {
  int tid = threadIdx.x;
  int c = blockIdx.x;
  if (c >= CHUNKS) {
    int i = (c - CHUNKS) * 1024 + tid;
    if (i < CVT_UNITS) {
      f32x4 v = ((const f32x4*)X)[i];
      u32x2 o;
      o[0] = f2bf(v[0]) | (f2bf(v[1]) << 16);
      o[1] = f2bf(v[2]) | (f2bf(v[3]) << 16);
      Xbf2[i] = o;
    }
    return;
  }
  __shared__ unsigned int pack[NW];
  // fused W fragment pack: slot s = (kb*8 + t)*64 + lane
  if (tid < 32) {
    int s = c * 32 + tid;
    int lane = s & 63;
    int t = (s >> 6) & 7;
    int kb = s >> 9;
    int col = t * 16 + (lane & 15);
    int k0 = kb * 32 + (lane >> 4) * 8;
    u32x4 o;
#pragma unroll
    for (int p = 0; p < 4; ++p) {
      unsigned lo = f2bf(W[(k0 + 2 * p) * 128 + col]);
      unsigned hi = f2bf(W[(k0 + 2 * p + 1) * 128 + col]);
      o[p] = lo | (hi << 16);
    }
    Wfrag[s] = o;
  }
  for (int w = tid; w < NW; w += 1024) pack[w] = 0;
  __syncthreads();
  int ebase = c * EPC;
  for (int i = tid; i < EPC; i += 1024) {
    int e = ebase + i;
    int d = dst[e];
    unsigned sh = (unsigned)(d & 7) * 4u;
    unsigned old = atomicAdd(&pack[d >> 3], 1u << sh);
    rank[e] = (unsigned char)((old >> sh) & 15u);
  }
  __syncthreads();
  for (int w = tid; w < NW; w += 1024) chunkcnt[(size_t)c * NW + w] = pack[w];
}

// Per-node exclusive scan over chunks -> u8 bases + total degree.
__global__ __launch_bounds__(256) void k_base(const unsigned int* __restrict__ chunkcnt,
                                              unsigned char* __restrict__ chunkbase,
                                              unsigned int* __restrict__ deg) {
  int d = blockIdx.x * 256 + threadIdx.x;
  if (d >= NN) return;
  int w = d >> 3;
  unsigned sh = (unsigned)(d & 7) * 4u;
  unsigned run = 0;
  for (int c = 0; c < CHUNKS; ++c) {
    unsigned v = (chunkcnt[(size_t)c * NW + w] >> sh) & 15u;
    chunkbase[(size_t)c * ND + d] = (unsigned char)run;
    run += v;
  }
  deg[d] = run;
}

// Fully parallel placement — no atomics.
__global__ __launch_bounds__(256) void k_place(const int* __restrict__ src,
                                               const int* __restrict__ dst,
                                               const unsigned char* __restrict__ rank,
                                               const unsigned char* __restrict__ chunkbase,
                                               int* __restrict__ slots) {
  int e = blockIdx.x * 256 + threadIdx.x;
  if (e >= NE) return;
  int c = e / EPC;
  int d = dst[e];
  int pos = (int)chunkbase[(size_t)c * ND + d] + (int)rank[e];
  if (pos < CAP) slots[d * CAP + pos] = src[e];
}

// One wave per node; edge ids via wave-uniform scalar loads; bf16 gather, f32 accum.
__global__ __launch_bounds__(256) void k_aggregate(const unsigned int* __restrict__ Xbf32,
                                                   const unsigned int* __restrict__ deg,
                                                   const int* __restrict__ slots,
                                                   unsigned int* __restrict__ Xnbr32) {
  int lane = threadIdx.x & 63;
  int node = __builtin_amdgcn_readfirstlane(blockIdx.x * 4 + (threadIdx.x >> 6));
  if (node >= NN) return;
  int dg = (int)deg[node];
  int m = min(dg, CAP);
  const int* sl = slots + node * CAP;
  float ax0 = 0.f, ay0 = 0.f, ax1 = 0.f, ay1 = 0.f;
  int e = 0;
  for (; e + 8 <= m; e += 8) {
    int s[8];
#pragma unroll
    for (int j = 0; j < 8; ++j) s[j] = __builtin_amdgcn_readfirstlane(sl[e + j]);
    unsigned v[8];
#pragma unroll
    for (int j = 0; j < 8; ++j) v[j] = Xbf32[s[j] * 64 + lane];
#pragma unroll
    for (int j = 0; j < 8; j += 2) {
      ax0 += bflo(v[j]);
      ay0 += bfhi(v[j]);
      ax1 += bflo(v[j + 1]);
      ay1 += bfhi(v[j + 1]);
    }
  }
  for (; e < m; ++e) {
    int s0 = __builtin_amdgcn_readfirstlane(sl[e]);
    unsigned v = Xbf32[s0 * 64 + lane];
    ax0 += bflo(v);
    ay0 += bfhi(v);
  }
  float inv = 1.0f / (float)max(dg, 1);
  float ax = (ax0 + ax1) * inv;
  float ay = (ay0 + ay1) * inv;
  Xnbr32[node * 64 + lane] = f2bf(ax) | (f2bf(ay) << 16);
}

// MFMA GEMM: out = relu(concat(X, Xnbr) @ W + b) * mask * 2
__global__ __launch_bounds__(512) void k_gemm(const unsigned short* __restrict__ Xbf,
                                              const unsigned short* __restrict__ Xnbr,
                                              const u32x4* __restrict__ Wfrag,
                                              const float* __restrict__ b,
                                              const int* __restrict__ mask,
                                              float* __restrict__ out) {
  int lane = threadIdx.x & 63;
  int wid = threadIdx.x >> 6;
  int tile = blockIdx.x * 8 + wid;
  if (tile >= NTILE) return;

  int row = tile * 16 + (lane & 15);
  const u32x4* a0 = (const u32x4*)(Xbf + (size_t)row * 128) + (lane >> 4);
  const u32x4* a1 = (const u32x4*)(Xnbr + (size_t)row * 128) + (lane >> 4);

  float bias[8];
#pragma unroll
  for (int t = 0; t < 8; ++t) bias[t] = b[t * 16 + (lane & 15)];

  f32x4 acc[8];
#pragma unroll
  for (int t = 0; t < 8; ++t) acc[t] = (f32x4){0.f, 0.f, 0.f, 0.f};

#pragma unroll
  for (int kb = 0; kb < 4; ++kb) {
    short8 a = __builtin_bit_cast(short8, a0[kb * 4]);
#pragma unroll
    for (int t = 0; t < 8; ++t) {
      short8 w = __builtin_bit_cast(short8, Wfrag[(kb * 8 + t) * 64 + lane]);
      acc[t] = __builtin_amdgcn_mfma_f32_16x16x32_bf16(a, w, acc[t], 0, 0, 0);
    }
  }
#pragma unroll
  for (int kb = 0; kb < 4; ++kb) {
    short8 a = __builtin_bit_cast(short8, a1[kb * 4]);
#pragma unroll
    for (int t = 0; t < 8; ++t) {
      short8 w = __builtin_bit_cast(short8, Wfrag[((kb + 4) * 8 + t) * 64 + lane]);
      acc[t] = __builtin_amdgcn_mfma_f32_16x16x32_bf16(a, w, acc[t], 0, 0, 0);
    }
  }

  int orow = tile * 16 + (lane >> 4) * 4;
  int ocol = lane & 15;
#pragma unroll
  for (int t = 0; t < 8; ++t) {
#pragma unroll
    for (int rg = 0; rg < 4; ++rg) {
      size_t idx = (size_t)(orow + rg) * 128 + t * 16 + ocol;
      float v = fmaxf(acc[t][rg] + bias[t], 0.f);
      int mk = mask[idx];
      out[idx] = v * (2.0f * (float)mk);
    }
  }
}

extern "C" void kernel_launch(void* const* d_in, const int* in_sizes, int n_in,
                              void* d_out, int out_size, void* d_ws, size_t ws_size,
                              hipStream_t stream) {
  (void)in_sizes; (void)n_in; (void)out_size; (void)ws_size;
  const float* X = (const float*)d_in[0];
  const float* W = (const float*)d_in[1];
  const float* b = (const float*)d_in[2];
  const int* src = (const int*)d_in[3];
  const int* dst = (const int*)d_in[4];
  const int* mask = (const int*)d_in[5];
  float* out = (float*)d_out;

  char* ws = (char*)d_ws;
  u32x4* Wfrag = (u32x4*)ws;
  unsigned int* deg = (unsigned int*)(ws + 65536);
  int* slots = (int*)(ws + 265728);
  unsigned short* Xbf = (unsigned short*)(ws + 11465728);
  unsigned int* Xbf32 = (unsigned int*)(ws + 11465728);
  u32x2* Xbf2 = (u32x2*)(ws + 11465728);
  unsigned int* Xnbr32 = (unsigned int*)(ws + 24265728);
  const unsigned short* Xnbr = (const unsigned short*)Xnbr32;
  // scratch overlapped inside the Xnbr region (dead before k_aggregate):
  unsigned char* rank = (unsigned char*)(ws + 24265728);
  unsigned int* chunkcnt = (unsigned int*)(ws + 25065728);
  unsigned char* chunkbase = (unsigned char*)(ws + 28268800);

  k_rankconv<<<CHUNKS + CVT_BLOCKS, 1024, 0, stream>>>(dst, W, X, rank, chunkcnt, Wfrag, Xbf2);
  k_base<<<(NN + 255) / 256, 256, 0, stream>>>(chunkcnt, chunkbase, deg);
  k_place<<<(NE + 255) / 256, 256, 0, stream>>>(src, dst, rank, chunkbase, slots);
  k_aggregate<<<NN / 4, 256, 0, stream>>>(Xbf32, deg, slots, Xnbr32);
  k_gemm<<<(NTILE + 7) / 8, 512, 0, stream>>>(Xbf, Xnbr, Wfrag, b, mask, out);
}

// Round 5
// 80.610 us; speedup vs baseline: 2.3118x; 1.1099x over previous
//
#include <hip/hip_runtime.h>

#define NN 50000
#define ND 50048   // padded node count (multiple of 8)
#define NW 6256    // ND/8 packed-nibble words
#define NE 800000
#define CHUNKS 32
#define EPC 25000  // NE / CHUNKS
#define CAP 56
#define NTILE 3125 // NN / 16
#define CVT_UNITS 1600000  // NN*128/4 (one f32x4 -> u32x2 per thread)
#define CVT_BLOCKS 1563    // covers CVT_UNITS + 32 zero-row units

typedef __attribute__((ext_vector_type(8))) short short8;
typedef __attribute__((ext_vector_type(4))) float f32x4;
typedef __attribute__((ext_vector_type(4))) unsigned int u32x4;
typedef __attribute__((ext_vector_type(2))) unsigned int u32x2;

// ws layout (bytes):
//   0           Wfrag     u32x4[4096]           65,536
//   65,536      deg       u32[ND]              200,192 ->    265,728
//   265,728     slots     int[NN*CAP]       11,200,000 -> 11,465,728
//   11,465,728  Xbf       bf16[(NN+1)*128]  12,800,256 -> 24,265,984  (row NN = zeros)
//   24,266,240  Xnbr      bf16[NN*128]      12,800,000 -> 37,066,240
//     overlapped inside Xnbr region (dead before k_aggregate writes Xnbr):
//     24,266,240  rank      u8[NE]              800,000 -> 25,066,240
//     25,066,240  chunkcnt  u32[CHUNKS*NW]      800,768 -> 25,867,008
//     25,867,008  chunkbase u8[CHUNKS*ND]     1,601,536 -> 27,468,544

__device__ __forceinline__ unsigned f2bf(float f) {  // RNE f32->bf16 (low 16 bits)
  unsigned u = __builtin_bit_cast(unsigned, f);
  return (u + 0x7fffu + ((u >> 16) & 1u)) >> 16;
}
__device__ __forceinline__ float bflo(unsigned u) {
  return __builtin_bit_cast(float, u << 16);
}
__device__ __forceinline__ float bfhi(unsigned u) {
  return __builtin_bit_cast(float, u & 0xffff0000u);
}

// blocks < CHUNKS: per-chunk edge ranking (packed-nibble LDS histogram) + W pack.
// blocks >= CHUNKS: X f32 -> bf16 conversion (+ zero row NN).
__global__ __launch_bounds__(1024) void k_rankconv(const int* __restrict__ dst,
                                                   const float* __restrict__ W,
                                                   const float* __restrict__ X,
                                                   unsigned char* __restrict__ rank,
                                                   unsigned int* __restrict__ chunkcnt,
                                                   u32x4* __restrict__ Wfrag,
                                                   u32x2* __restrict__ Xbf2) {
  int tid = threadIdx.x;
  int c = blockIdx.x;
  if (c >= CHUNKS) {
    int i = (c - CHUNKS) * 1024 + tid;
    if (i < CVT_UNITS) {
      f32x4 v = ((const f32x4*)X)[i];
      u32x2 o;
      o[0] = f2bf(v[0]) | (f2bf(v[1]) << 16);
      o[1] = f2bf(v[2]) | (f2bf(v[3]) << 16);
      Xbf2[i] = o;
    } else if (i < CVT_UNITS + 32) {
      Xbf2[i] = (u32x2){0u, 0u};  // zero row (node index NN)
    }
    return;
  }
  __shared__ unsigned int pack[NW];
  // fused W fragment pack: slot s = (kb*8 + t)*64 + lane
  if (tid < 128) {
    int s = c * 128 + tid;
    int lane = s & 63;
    int t = (s >> 6) & 7;
    int kb = s >> 9;
    int col = t * 16 + (lane & 15);
    int k0 = kb * 32 + (lane >> 4) * 8;
    u32x4 o;
#pragma unroll
    for (int p = 0; p < 4; ++p) {
      unsigned lo = f2bf(W[(k0 + 2 * p) * 128 + col]);
      unsigned hi = f2bf(W[(k0 + 2 * p + 1) * 128 + col]);
      o[p] = lo | (hi << 16);
    }
    Wfrag[s] = o;
  }
  for (int w = tid; w < NW; w += 1024) pack[w] = 0;
  __syncthreads();
  int ebase = c * EPC;
  for (int i = tid; i < EPC; i += 1024) {
    int e = ebase + i;
    int d = dst[e];
    unsigned sh = (unsigned)(d & 7) * 4u;
    unsigned old = atomicAdd(&pack[d >> 3], 1u << sh);
    rank[e] = (unsigned char)((old >> sh) & 15u);
  }
  __syncthreads();
  for (int w = tid; w < NW; w += 1024) chunkcnt[(size_t)c * NW + w] = pack[w];
}

// Per-node exclusive scan over chunks (fully unrolled, independent loads).
__global__ __launch_bounds__(64) void k_base(const unsigned int* __restrict__ chunkcnt,
                                             unsigned char* __restrict__ chunkbase,
                                             unsigned int* __restrict__ deg) {
  int d = blockIdx.x * 64 + threadIdx.x;
  if (d >= NN) return;
  int w = d >> 3;
  unsigned sh = (unsigned)(d & 7) * 4u;
  unsigned cnts[CHUNKS];
#pragma unroll
  for (int c = 0; c < CHUNKS; ++c) cnts[c] = chunkcnt[(size_t)c * NW + w];
  unsigned run = 0;
#pragma unroll
  for (int c = 0; c < CHUNKS; ++c) {
    chunkbase[(size_t)c * ND + d] = (unsigned char)run;
    run += (cnts[c] >> sh) & 15u;
  }
  deg[d] = run;
}

// Fully parallel placement — no atomics.
__global__ __launch_bounds__(256) void k_place(const int* __restrict__ src,
                                               const int* __restrict__ dst,
                                               const unsigned char* __restrict__ rank,
                                               const unsigned char* __restrict__ chunkbase,
                                               int* __restrict__ slots) {
  int e = blockIdx.x * 256 + threadIdx.x;
  if (e >= NE) return;
  int c = e / EPC;
  int d = dst[e];
  int pos = (int)chunkbase[(size_t)c * ND + d] + (int)rank[e];
  if (pos < CAP) slots[d * CAP + pos] = src[e];
}

// One wave per node; 4 edges per load instruction (16 lanes x 16B per row);
// depth-2 pipeline; invalid edge slots read the zero row (node NN).
__global__ __launch_bounds__(256) void k_aggregate(const u32x4* __restrict__ Xbf4,
                                                   const unsigned int* __restrict__ deg,
                                                   const int* __restrict__ slots,
                                                   u32x4* __restrict__ Xnbr4) {
  int lane = threadIdx.x & 63;
  int node = blockIdx.x * 4 + (threadIdx.x >> 6);
  int g = lane >> 4;  // edge group 0..3
  int i = lane & 15;  // 16B offset within row
  int dg = (int)deg[node];
  int m = min(dg, CAP);
  const int* sl = slots + node * CAP;
  int s_pre = sl[min(lane, CAP - 1)];
  float acc[8] = {0.f, 0.f, 0.f, 0.f, 0.f, 0.f, 0.f, 0.f};

#define LOADB(bb, dstv)                                   \
  {                                                       \
    int e_ = (bb) * 4 + g;                                \
    int s_ = __shfl(s_pre, min(e_, CAP - 1), 64);         \
    s_ = (e_ < m) ? s_ : NN;                              \
    dstv = Xbf4[(size_t)s_ * 16 + i];                     \
  }
#define ACC(v)                                            \
  {                                                       \
    acc[0] += bflo(v[0]); acc[1] += bfhi(v[0]);           \
    acc[2] += bflo(v[1]); acc[3] += bfhi(v[1]);           \
    acc[4] += bflo(v[2]); acc[5] += bfhi(v[2]);           \
    acc[6] += bflo(v[3]); acc[7] += bfhi(v[3]);           \
  }

  int nb = (m + 3) >> 2;
  if (nb > 0) {
    u32x4 cur;
    LOADB(0, cur);
    if (nb > 1) {
      u32x4 nxt;
      LOADB(1, nxt);
      for (int bb = 2; bb < nb; ++bb) {
        u32x4 n2;
        LOADB(bb, n2);
        ACC(cur);
        cur = nxt;
        nxt = n2;
      }
      ACC(cur);
      cur = nxt;
    }
    ACC(cur);
  }
#undef LOADB
#undef ACC

#pragma unroll
  for (int k = 0; k < 8; ++k) acc[k] += __shfl_xor(acc[k], 16, 64);
#pragma unroll
  for (int k = 0; k < 8; ++k) acc[k] += __shfl_xor(acc[k], 32, 64);

  float inv = 1.0f / (float)max(dg, 1);
  if (lane < 16) {
    u32x4 o;
    o[0] = f2bf(acc[0] * inv) | (f2bf(acc[1] * inv) << 16);
    o[1] = f2bf(acc[2] * inv) | (f2bf(acc[3] * inv) << 16);
    o[2] = f2bf(acc[4] * inv) | (f2bf(acc[5] * inv) << 16);
    o[3] = f2bf(acc[6] * inv) | (f2bf(acc[7] * inv) << 16);
    Xnbr4[(size_t)node * 16 + i] = o;
  }
}

// MFMA GEMM: out = relu(concat(X, Xnbr) @ W + b) * mask * 2
__global__ __launch_bounds__(512) void k_gemm(const unsigned short* __restrict__ Xbf,
                                              const unsigned short* __restrict__ Xnbr,
                                              const u32x4* __restrict__ Wfrag,
                                              const float* __restrict__ b,
                                              const int* __restrict__ mask,
                                              float* __restrict__ out) {
  int lane = threadIdx.x & 63;
  int wid = threadIdx.x >> 6;
  int tile = blockIdx.x * 8 + wid;
  if (tile >= NTILE) return;

  int row = tile * 16 + (lane & 15);
  const u32x4* a0 = (const u32x4*)(Xbf + (size_t)row * 128) + (lane >> 4);
  const u32x4* a1 = (const u32x4*)(Xnbr + (size_t)row * 128) + (lane >> 4);

  float bias[8];
#pragma unroll
  for (int t = 0; t < 8; ++t) bias[t] = b[t * 16 + (lane & 15)];

  f32x4 acc[8];
#pragma unroll
  for (int t = 0; t < 8; ++t) acc[t] = (f32x4){0.f, 0.f, 0.f, 0.f};

#pragma unroll
  for (int kb = 0; kb < 4; ++kb) {
    short8 a = __builtin_bit_cast(short8, a0[kb * 4]);
#pragma unroll
    for (int t = 0; t < 8; ++t) {
      short8 w = __builtin_bit_cast(short8, Wfrag[(kb * 8 + t) * 64 + lane]);
      acc[t] = __builtin_amdgcn_mfma_f32_16x16x32_bf16(a, w, acc[t], 0, 0, 0);
    }
  }
#pragma unroll
  for (int kb = 0; kb < 4; ++kb) {
    short8 a = __builtin_bit_cast(short8, a1[kb * 4]);
#pragma unroll
    for (int t = 0; t < 8; ++t) {
      short8 w = __builtin_bit_cast(short8, Wfrag[((kb + 4) * 8 + t) * 64 + lane]);
      acc[t] = __builtin_amdgcn_mfma_f32_16x16x32_bf16(a, w, acc[t], 0, 0, 0);
    }
  }

  int orow = tile * 16 + (lane >> 4) * 4;
  int ocol = lane & 15;
#pragma unroll
  for (int t = 0; t < 8; ++t) {
#pragma unroll
    for (int rg = 0; rg < 4; ++rg) {
      size_t idx = (size_t)(orow + rg) * 128 + t * 16 + ocol;
      float v = fmaxf(acc[t][rg] + bias[t], 0.f);
      int mk = mask[idx];
      out[idx] = v * (2.0f * (float)mk);
    }
  }
}

extern "C" void kernel_launch(void* const* d_in, const int* in_sizes, int n_in,
                              void* d_out, int out_size, void* d_ws, size_t ws_size,
                              hipStream_t stream) {
  (void)in_sizes; (void)n_in; (void)out_size; (void)ws_size;
  const float* X = (const float*)d_in[0];
  const float* W = (const float*)d_in[1];
  const float* b = (const float*)d_in[2];
  const int* src = (const int*)d_in[3];
  const int* dst = (const int*)d_in[4];
  const int* mask = (const int*)d_in[5];
  float* out = (float*)d_out;

  char* ws = (char*)d_ws;
  u32x4* Wfrag = (u32x4*)ws;
  unsigned int* deg = (unsigned int*)(ws + 65536);
  int* slots = (int*)(ws + 265728);
  unsigned short* Xbf = (unsigned short*)(ws + 11465728);
  u32x2* Xbf2 = (u32x2*)(ws + 11465728);
  const u32x4* Xbf4 = (const u32x4*)(ws + 11465728);
  u32x4* Xnbr4 = (u32x4*)(ws + 24266240);
  const unsigned short* Xnbr = (const unsigned short*)(ws + 24266240);
  // scratch overlapped inside the Xnbr region (dead before k_aggregate):
  unsigned char* rank = (unsigned char*)(ws + 24266240);
  unsigned int* chunkcnt = (unsigned int*)(ws + 25066240);
  unsigned char* chunkbase = (unsigned char*)(ws + 25867008);

  k_rankconv<<<CHUNKS + CVT_BLOCKS, 1024, 0, stream>>>(dst, W, X, rank, chunkcnt, Wfrag, Xbf2);
  k_base<<<(NN + 63) / 64, 64, 0, stream>>>(chunkcnt, chunkbase, deg);
  k_place<<<(NE + 255) / 256, 256, 0, stream>>>(src, dst, rank, chunkbase, slots);
  k_aggregate<<<NN / 4, 256, 0, stream>>>(Xbf4, deg, slots, Xnbr4);
  k_gemm<<<(NTILE + 7) / 8, 512, 0, stream>>>(Xbf, Xnbr, Wfrag, b, mask, out);
}